// Round 3
// baseline (472.222 us; speedup 1.0000x reference)
//
#include <hip/hip_runtime.h>

// UAG_RNN v7: v6 + (a) 128B-stride XOR-swizzled LDS tiles (bank-conflict fix),
// (b) v_cvt_pk_bf16_f32 packing (VALU cut), (c) yr kept in registers with
// use-layout loads; yl LDS only serves the shifted row, (d) gamma folded into
// WT/bT (exact: gamma=0.5), pad-row zeros handle the shift boundary.
// B=8, C=64, H=128, W=128.

#define B_ 8
#define C_ 64
#define H_ 128
#define W_ 128
#define HW_ (H_*W_)      // 16384
#define CHW_ (C_*HW_)    // 1048576
#define TOT_ (B_*CHW_)   // 8388608

typedef __attribute__((ext_vector_type(8))) short bfrag;
typedef __attribute__((ext_vector_type(4))) float f4_t;

// LDS-ordering barrier: flush own DS ops, then workgroup barrier. Does NOT
// drain vmcnt — global prefetch loads / stores stay in flight across steps.
#define LDS_BARRIER() do { \
    asm volatile("s_waitcnt lgkmcnt(0)" ::: "memory"); \
    __builtin_amdgcn_s_barrier(); \
} while (0)

#define WAVE_LDS_FENCE() asm volatile("s_waitcnt lgkmcnt(0)" ::: "memory")

__device__ inline unsigned short bfr(float f) {
    unsigned int u = __float_as_uint(f);
    u += 0x7fffu + ((u >> 16) & 1u);
    return (unsigned short)(u >> 16);
}
__device__ inline float b2f(unsigned short u) {
    return __uint_as_float(((unsigned int)u) << 16);
}
// HW packed f32->bf16 (RNE, identical to bfr)
__device__ inline unsigned int cvtpk(float lo, float hi) {
    unsigned int r;
    asm("v_cvt_pk_bf16_f32 %0, %1, %2" : "=v"(r) : "v"(lo), "v"(hi));
    return r;
}
__device__ inline bfrag packf(float4 a, float4 b) {
    bfrag r;
    r[0]=(short)bfr(a.x); r[1]=(short)bfr(a.y); r[2]=(short)bfr(a.z); r[3]=(short)bfr(a.w);
    r[4]=(short)bfr(b.x); r[5]=(short)bfr(b.y); r[6]=(short)bfr(b.z); r[7]=(short)bfr(b.w);
    return r;
}
__device__ inline bfrag packfs(float4 a, float4 b, float s) {
    bfrag r;
    r[0]=(short)bfr(s*a.x); r[1]=(short)bfr(s*a.y); r[2]=(short)bfr(s*a.z); r[3]=(short)bfr(s*a.w);
    r[4]=(short)bfr(s*b.x); r[5]=(short)bfr(s*b.y); r[6]=(short)bfr(s*b.z); r[7]=(short)bfr(s*b.w);
    return r;
}
__device__ inline unsigned int relu2(unsigned int w) {
    unsigned int lo = (w & 0x8000u) ? 0u : (w & 0xffffu);
    unsigned int hi = (w & 0x80000000u) ? 0u : (w & 0xffff0000u);
    return lo | hi;
}
__device__ inline uint4 relu8(uint4 v) {
    v.x = relu2(v.x); v.y = relu2(v.y); v.z = relu2(v.z); v.w = relu2(v.w);
    return v;
}
// XOR slot swizzle: rows are 64 shorts (128B) = 8 slots of 16B; swizzle slot
// by (row&7) so a wave's per-lane rows spread across all 8 slots.
__device__ inline int swz(int r, int s) {
    return (((s >> 3) ^ (r & 7)) << 3) | (s & 7);
}

#define MFMA __builtin_amdgcn_mfma_f32_16x16x32_bf16

// x,y NCHW fp32 -> NHWC bf16 (x2 / y2b)
__global__ void k_prep(const float* __restrict__ x, const float* __restrict__ y,
                       unsigned short* __restrict__ y2b, unsigned short* __restrict__ x2) {
    __shared__ float t[64][65];
    int blk = blockIdx.x;
    int isx = blk >> 11; blk &= 2047;
    int b = blk >> 8, hw0 = (blk & 255) * 64;
    int cq = threadIdx.x >> 6, lo = threadIdx.x & 63;
    const float* ip = (isx ? x : y) + (size_t)b * CHW_;
#pragma unroll
    for (int p = 0; p < 16; p++) {
        int c = p * 4 + cq;
        t[c][lo] = ip[(size_t)c * HW_ + hw0 + lo];
    }
    __syncthreads();
    unsigned short* op = (isx ? x2 : y2b) + (size_t)b * CHW_;
#pragma unroll
    for (int p = 0; p < 16; p++) {
        int hw = p * 4 + cq;
        op[(size_t)(hw0 + hw) * 64 + lo] = bfr(t[lo][hw]);
    }
}

// sum 4 bf16 NHWC dir buffers -> out NCHW fp32
__global__ void k_tb(const unsigned short* __restrict__ i0, const unsigned short* __restrict__ i1,
                     const unsigned short* __restrict__ i2, const unsigned short* __restrict__ i3,
                     float* __restrict__ outp) {
    __shared__ float t[64][65];
    int blk = blockIdx.x;
    int b = blk >> 8, hw0 = (blk & 255) * 64;
    int tid = threadIdx.x;
    size_t bb = (size_t)b * CHW_;
    int hwi = tid >> 4, c4 = (tid & 15) * 4;
#pragma unroll
    for (int p = 0; p < 4; p++) {
        int hw = p * 16 + hwi;
        size_t s = bb + (size_t)(hw0 + hw) * 64 + c4;
        uint2 u0 = *(const uint2*)(i0 + s);
        uint2 u1 = *(const uint2*)(i1 + s);
        uint2 u2 = *(const uint2*)(i2 + s);
        uint2 u3 = *(const uint2*)(i3 + s);
        float v0 = b2f((unsigned short)(u0.x & 0xffffu)) + b2f((unsigned short)(u1.x & 0xffffu))
                 + b2f((unsigned short)(u2.x & 0xffffu)) + b2f((unsigned short)(u3.x & 0xffffu));
        float v1 = b2f((unsigned short)(u0.x >> 16)) + b2f((unsigned short)(u1.x >> 16))
                 + b2f((unsigned short)(u2.x >> 16)) + b2f((unsigned short)(u3.x >> 16));
        float v2 = b2f((unsigned short)(u0.y & 0xffffu)) + b2f((unsigned short)(u1.y & 0xffffu))
                 + b2f((unsigned short)(u2.y & 0xffffu)) + b2f((unsigned short)(u3.y & 0xffffu));
        float v3 = b2f((unsigned short)(u0.y >> 16)) + b2f((unsigned short)(u1.y >> 16))
                 + b2f((unsigned short)(u2.y >> 16)) + b2f((unsigned short)(u3.y >> 16));
        t[hw][c4 + 0] = v0; t[hw][c4 + 1] = v1; t[hw][c4 + 2] = v2; t[hw][c4 + 3] = v3;
    }
    __syncthreads();
    float* op = outp + bb;
    int cq = tid >> 6, lo = tid & 63;
#pragma unroll
    for (int p = 0; p < 16; p++) {
        int c = p * 4 + cq;
        op[(size_t)c * HW_ + hw0 + lo] = t[lo][c];
    }
}

// Row scans: grid 128 = s(2) x b(8) x wb(8 of width 16). 1 wave/block.
__global__ __launch_bounds__(64) void k_rowscan(
        const unsigned short* __restrict__ x2, const unsigned short* __restrict__ y2b,
        const float* __restrict__ Wc, const float* __restrict__ bc,
        unsigned short* __restrict__ hs2, unsigned short* __restrict__ hn2) {
    int bid = blockIdx.x;
    int s = bid >> 6, b = (bid >> 3) & 7, wb = bid & 7;
    int w0 = wb * 16;
    int lane = threadIdx.x, q = lane >> 4, n = lane & 15;
    int ka = s ? 8 : 0, kb = ka + 1;

    bfrag WaF[4][2], WbF[4][2];
#pragma unroll
    for (int mt = 0; mt < 4; mt++)
#pragma unroll
        for (int kc = 0; kc < 2; kc++) {
            const float* wp = Wc + (size_t)(ka * 64 + mt * 16 + n) * 64 + kc * 32 + q * 8;
            WaF[mt][kc] = packf(*(const float4*)wp, *(const float4*)(wp + 4));
            const float* wq2 = Wc + (size_t)(kb * 64 + mt * 16 + n) * 64 + kc * 32 + q * 8;
            WbF[mt][kc] = packf(*(const float4*)wq2, *(const float4*)(wq2 + 4));
        }
    f4_t baR[4], bbR[4];
#pragma unroll
    for (int mt = 0; mt < 4; mt++) {
        float4 ta = *(const float4*)&bc[ka * 64 + mt * 16 + q * 4];
        float4 tb = *(const float4*)&bc[kb * 64 + mt * 16 + q * 4];
        baR[mt] = f4_t{ta.x, ta.y, ta.z, ta.w};
        bbR[mt] = f4_t{tb.x, tb.y, tb.z, tb.w};
    }

    const unsigned short* xb = x2 + (size_t)b * CHW_;
    const unsigned short* yb = y2b + (size_t)b * CHW_;
    unsigned short* dT = (s ? hn2 : hs2) + (size_t)b * CHW_;

    __shared__ __align__(16) unsigned short stt[2][16][72];

    int row0 = s ? 127 : 0;
    {
        const unsigned short* sp = xb + (size_t)(row0 * 128 + w0 + n) * 64 + q * 16;
        uint4 v0 = *(const uint4*)sp;
        uint4 v1 = *(const uint4*)(sp + 8);
        if (s) { v0 = relu8(v0); v1 = relu8(v1); }
        *(uint4*)&stt[0][n][q * 16] = v0;
        *(uint4*)&stt[0][n][q * 16 + 8] = v1;
        unsigned short* op = dT + (size_t)(row0 * 128 + w0 + n) * 64 + q * 16;
        *(uint4*)op = v0;
        *(uint4*)(op + 8) = v1;
    }

    // prefetch i=1
    uint4 xf0, xf1; ushort4 yv[4];
    {
        int row1 = s ? 126 : 1;
        const unsigned short* sp = xb + (size_t)(row1 * 128 + w0 + n) * 64 + q * 8;
        xf0 = *(const uint4*)sp;
        xf1 = *(const uint4*)(sp + 32);
#pragma unroll
        for (int mt = 0; mt < 4; mt++)
            yv[mt] = *(const ushort4*)&yb[(size_t)(row0 * 128 + w0 + n) * 64 + mt * 16 + q * 4];
    }
    WAVE_LDS_FENCE();

    for (int i = 1; i < 128; i++) {
        int row = s ? 127 - i : i;
        int rd = (i - 1) & 1, wr = i & 1;

        bfrag fb0 = *(const bfrag*)&stt[rd][n][q * 8];
        bfrag fb1 = *(const bfrag*)&stt[rd][n][32 + q * 8];
        bfrag fa0 = *(const bfrag*)&xf0;
        bfrag fa1 = *(const bfrag*)&xf1;

        // EARLY prefetch issue (before MFMA's vmcnt wait on xf/yv)
        uint4 xn0, xn1; ushort4 yn[4];
        if (i < 127) {
            int rowN = s ? 127 - (i + 1) : i + 1;
            int yrowN = s ? rowN + 1 : rowN - 1;
            const unsigned short* sp = xb + (size_t)(rowN * 128 + w0 + n) * 64 + q * 8;
            xn0 = *(const uint4*)sp;
            xn1 = *(const uint4*)(sp + 32);
#pragma unroll
            for (int mt = 0; mt < 4; mt++)
                yn[mt] = *(const ushort4*)&yb[(size_t)(yrowN * 128 + w0 + n) * 64 + mt * 16 + q * 4];
        }

        f4_t DA[4], DB[4];
#pragma unroll
        for (int mt = 0; mt < 4; mt++) {
            DA[mt] = MFMA(WaF[mt][0], fa0, baR[mt], 0, 0, 0);
            DA[mt] = MFMA(WaF[mt][1], fa1, DA[mt], 0, 0, 0);
            DB[mt] = MFMA(WbF[mt][0], fb0, bbR[mt], 0, 0, 0);
            DB[mt] = MFMA(WbF[mt][1], fb1, DB[mt], 0, 0, 0);
        }

#pragma unroll
        for (int mt = 0; mt < 4; mt++) {
            float h0 = fmaxf(fmaf(DB[mt][0], b2f(yv[mt].x), DA[mt][0]), 0.f);
            float h1 = fmaxf(fmaf(DB[mt][1], b2f(yv[mt].y), DA[mt][1]), 0.f);
            float h2 = fmaxf(fmaf(DB[mt][2], b2f(yv[mt].z), DA[mt][2]), 0.f);
            float h3 = fmaxf(fmaf(DB[mt][3], b2f(yv[mt].w), DA[mt][3]), 0.f);
            uint2 pk; pk.x = cvtpk(h0, h1); pk.y = cvtpk(h2, h3);
            *(uint2*)&stt[wr][n][mt * 16 + q * 4] = pk;
            *(uint2*)&dT[(size_t)(row * 128 + w0 + n) * 64 + mt * 16 + q * 4] = pk;
        }
        if (i < 127) {
            xf0 = xn0; xf1 = xn1;
#pragma unroll
            for (int mt = 0; mt < 4; mt++) yv[mt] = yn[mt];
        }
        WAVE_LDS_FENCE();
    }
}

// Col scans: grid 32 = d(4) x b(8). 512 threads = 8 waves.
// State + shifted-y in XOR-swizzled 128B-stride LDS; yr in registers;
// gamma folded into WT/bT; outputs bf16.
__global__ __launch_bounds__(512, 2) void k_colscan(
        const unsigned short* __restrict__ y2b,
        const unsigned short* __restrict__ hs2, const unsigned short* __restrict__ hn2,
        const float* __restrict__ Wc, const float* __restrict__ bc,
        const float* __restrict__ gam,
        unsigned short* __restrict__ outD) {
    int bid = blockIdx.x;
    int d = bid >> 3, b = bid & 7;
    int tid = threadIdx.x;
    int wave = tid >> 6, lane = tid & 63, q = lane >> 4, n = lane & 15;
    int row = wave * 16 + n;
    int down = (d < 2) ? 1 : 0;
    int flip = d & 1;
    const unsigned short* base2 = ((d < 2) ? hs2 : hn2) + (size_t)b * CHW_;
    int kt, ka, kb;
    if (d == 0)      { kt = 2;  ka = 3;  kb = 4;  }
    else if (d == 1) { kt = 5;  ka = 6;  kb = 7;  }
    else if (d == 2) { kt = 10; ka = 11; kb = 12; }
    else             { kt = 13; ka = 14; kb = 15; }
    float g = gam[d];

    bfrag WA[4][2], WB[4][2], WT[4][2];
#pragma unroll
    for (int mt = 0; mt < 4; mt++)
#pragma unroll
        for (int kc = 0; kc < 2; kc++) {
            const float* wa = Wc + (size_t)(ka * 64 + mt * 16 + n) * 64 + kc * 32 + q * 8;
            const float* wb = Wc + (size_t)(kb * 64 + mt * 16 + n) * 64 + kc * 32 + q * 8;
            const float* wt = Wc + (size_t)(kt * 64 + mt * 16 + n) * 64 + kc * 32 + q * 8;
            WA[mt][kc] = packf(*(const float4*)wa, *(const float4*)(wa + 4));
            WB[mt][kc] = packf(*(const float4*)wb, *(const float4*)(wb + 4));
            // gamma folded into WT (gamma = 0.5 -> exact scaling)
            WT[mt][kc] = packfs(*(const float4*)wt, *(const float4*)(wt + 4), g);
        }
    f4_t bAr[4], bBr[4], bTr[4];
#pragma unroll
    for (int mt = 0; mt < 4; mt++) {
        float4 ta = *(const float4*)&bc[ka * 64 + mt * 16 + q * 4];
        float4 tb = *(const float4*)&bc[kb * 64 + mt * 16 + q * 4];
        float4 tt = *(const float4*)&bc[kt * 64 + mt * 16 + q * 4];
        bAr[mt] = f4_t{ta.x, ta.y, ta.z, ta.w};
        bBr[mt] = f4_t{tb.x, tb.y, tb.z, tb.w};
        bTr[mt] = f4_t{g * tt.x, g * tt.y, g * tt.z, g * tt.w};
    }

    const unsigned short* yB = y2b + (size_t)b * CHW_;
    unsigned short* oB = outD + (size_t)d * TOT_ + (size_t)b * CHW_;

    // 128B-stride rows + XOR slot swizzle; rows 0 and 129 are zero pads that
    // implement the spatial shift boundary (term becomes 0 via ys=0).
    __shared__ __align__(16) unsigned short stt[2][130][64];
    __shared__ __align__(16) unsigned short yl[2][130][64];
    for (int idx = tid; idx < 2 * 2 * 64; idx += 512) {
        int buf = idx >> 7, hi = (idx >> 6) & 1, t = idx & 63;
        stt[buf][hi ? 129 : 0][t] = 0;
        yl[buf][hi ? 129 : 0][t] = 0;
    }

    // ---- j = 0 : c0 = relu(base col0)
    int c0 = flip ? 127 : 0;
    {
        const unsigned short* sp = base2 + (size_t)(row * 128 + c0) * 64 + q * 16;
        uint4 v0 = relu8(*(const uint4*)sp);
        uint4 v1 = relu8(*(const uint4*)(sp + 8));
        *(uint4*)&stt[0][row + 1][swz(row + 1, q * 16)] = v0;
        *(uint4*)&stt[0][row + 1][swz(row + 1, q * 16 + 8)] = v1;
        unsigned short* op = oB + (size_t)(row * 128 + c0) * 64 + q * 16;
        *(uint4*)op = v0;
        *(uint4*)(op + 8) = v1;
    }

    int srow = down ? row : row + 2;   // shifted-state LDS row (incl. +1 pad)

    // y register pipeline (use-layout): ycur = y col yc(1), ynext = y col yc(2)
    ushort4 ycur[4], ynext[4];
    {
        int yc1 = flip ? 127 : 0;
        int yc2 = flip ? 126 : 1;
#pragma unroll
        for (int mt = 0; mt < 4; mt++) {
            ycur[mt]  = *(const ushort4*)&yB[(size_t)(row * 128 + yc1) * 64 + mt * 16 + q * 4];
            ynext[mt] = *(const ushort4*)&yB[(size_t)(row * 128 + yc2) * 64 + mt * 16 + q * 4];
        }
        // stage yl[0] (col yc(1)) from ycur
#pragma unroll
        for (int mt = 0; mt < 4; mt++)
            *(ushort4*)&yl[0][row + 1][swz(row + 1, mt * 16 + q * 4)] = ycur[mt];
    }

    // prefetch base col c(1)
    uint4 pb0, pb1;
    {
        int c1 = flip ? 126 : 1;
        const unsigned short* sp = base2 + (size_t)(row * 128 + c1) * 64 + q * 8;
        pb0 = *(const uint4*)sp;
        pb1 = *(const uint4*)(sp + 32);
    }
    LDS_BARRIER();

    for (int j = 1; j < 128; j++) {
        int cj = flip ? 127 - j : j;
        int rd = (j - 1) & 1, wr = j & 1;

        // LDS reads: state frags (own + shifted row) + shifted-row y
        bfrag fb0 = *(const bfrag*)&stt[rd][row + 1][swz(row + 1, q * 8)];
        bfrag fb1 = *(const bfrag*)&stt[rd][row + 1][swz(row + 1, 32 + q * 8)];
        bfrag ft0 = *(const bfrag*)&stt[rd][srow][swz(srow, q * 8)];
        bfrag ft1 = *(const bfrag*)&stt[rd][srow][swz(srow, 32 + q * 8)];
        ushort4 ysu[4];
#pragma unroll
        for (int mt = 0; mt < 4; mt++)
            ysu[mt] = *(const ushort4*)&yl[rd][srow][swz(srow, mt * 16 + q * 4)];
        bfrag fa0 = *(const bfrag*)&pb0;
        bfrag fa1 = *(const bfrag*)&pb1;

        f4_t DA[4], DB[4], DT[4];
#pragma unroll
        for (int mt = 0; mt < 4; mt++) {
            DA[mt] = MFMA(WA[mt][0], fa0, bAr[mt], 0, 0, 0);
            DA[mt] = MFMA(WA[mt][1], fa1, DA[mt], 0, 0, 0);
            DB[mt] = MFMA(WB[mt][0], fb0, bBr[mt], 0, 0, 0);
            DB[mt] = MFMA(WB[mt][1], fb1, DB[mt], 0, 0, 0);
            DT[mt] = MFMA(WT[mt][0], ft0, bTr[mt], 0, 0, 0);
            DT[mt] = MFMA(WT[mt][1], ft1, DT[mt], 0, 0, 0);
        }

        // stage y col yc(j+1) from ynext; reload pb <- base col c(j+1);
        // load ynew <- y col yc(j+2). All issued before the finalize waits.
        if (j < 127) {
#pragma unroll
            for (int mt = 0; mt < 4; mt++)
                *(ushort4*)&yl[wr][row + 1][swz(row + 1, mt * 16 + q * 4)] = ynext[mt];
            int cN = flip ? 126 - j : j + 1;
            const unsigned short* sp = base2 + (size_t)(row * 128 + cN) * 64 + q * 8;
            pb0 = *(const uint4*)sp;
            pb1 = *(const uint4*)(sp + 32);
        }
        ushort4 ynew[4];
        if (j < 126) {
            int ycN = flip ? 126 - j : j + 1;
#pragma unroll
            for (int mt = 0; mt < 4; mt++)
                ynew[mt] = *(const ushort4*)&yB[(size_t)(row * 128 + ycN) * 64 + mt * 16 + q * 4];
        }

        // finalize: h = relu(DA + DB*yr + DT*ys)   (gamma pre-folded; ys=0 at
        // the shift boundary via the zeroed pad rows)
#pragma unroll
        for (int mt = 0; mt < 4; mt++) {
            float h0 = fmaxf(fmaf(DT[mt][0], b2f(ysu[mt].x), fmaf(DB[mt][0], b2f(ycur[mt].x), DA[mt][0])), 0.f);
            float h1 = fmaxf(fmaf(DT[mt][1], b2f(ysu[mt].y), fmaf(DB[mt][1], b2f(ycur[mt].y), DA[mt][1])), 0.f);
            float h2 = fmaxf(fmaf(DT[mt][2], b2f(ysu[mt].z), fmaf(DB[mt][2], b2f(ycur[mt].z), DA[mt][2])), 0.f);
            float h3 = fmaxf(fmaf(DT[mt][3], b2f(ysu[mt].w), fmaf(DB[mt][3], b2f(ycur[mt].w), DA[mt][3])), 0.f);
            uint2 pk; pk.x = cvtpk(h0, h1); pk.y = cvtpk(h2, h3);
            *(uint2*)&stt[wr][row + 1][swz(row + 1, mt * 16 + q * 4)] = pk;
            *(uint2*)&oB[(size_t)(row * 128 + cj) * 64 + mt * 16 + q * 4] = pk;
        }
        if (j < 127) {
#pragma unroll
            for (int mt = 0; mt < 4; mt++) { ycur[mt] = ynext[mt]; ynext[mt] = ynew[mt]; }
        }
        LDS_BARRIER();
    }
}

extern "C" void kernel_launch(void* const* d_in, const int* in_sizes, int n_in,
                              void* d_out, int out_size, void* d_ws, size_t ws_size,
                              hipStream_t stream) {
    const float* x   = (const float*)d_in[0];
    const float* y   = (const float*)d_in[1];
    const float* Wc  = (const float*)d_in[2];
    const float* bc  = (const float*)d_in[3];
    const float* gam = (const float*)d_in[4];
    float* out = (float*)d_out;

    // ws layout (all bf16): x2, y2b, hs2, hn2 (TOT_ each), outD (4x TOT_)
    unsigned short* x2  = (unsigned short*)d_ws;
    unsigned short* y2b = x2 + (size_t)TOT_;
    unsigned short* hs2 = y2b + (size_t)TOT_;
    unsigned short* hn2 = hs2 + (size_t)TOT_;
    unsigned short* outD = hn2 + (size_t)TOT_;

    hipLaunchKernelGGL(k_prep, dim3(4096), dim3(256), 0, stream, x, y, y2b, x2);
    hipLaunchKernelGGL(k_rowscan, dim3(128), dim3(64), 0, stream, x2, y2b, Wc, bc, hs2, hn2);
    hipLaunchKernelGGL(k_colscan, dim3(32), dim3(512), 0, stream, y2b, hs2, hn2, Wc, bc, gam, outD);
    hipLaunchKernelGGL(k_tb, dim3(2048), dim3(256), 0, stream,
                       outD, outD + (size_t)TOT_, outD + 2 * (size_t)TOT_,
                       outD + 3 * (size_t)TOT_, out);
}